// Round 1
// baseline (161.771 us; speedup 1.0000x reference)
//
#include <hip/hip_runtime.h>

// RepulsionXTB: per-pair repulsion energy, segment-summed per molecule.
//
// Inputs (setup_inputs order, harness converts ints to int32):
//   d_in[0] element_idxs  int32  [M*A]   (M=2048, A=64 -> 131072)
//   d_in[1] neighbor_idxs int32  [2*P]   (P=8388608)
//   d_in[2] distances     f32    [P]
//   d_in[3] y_ab          f32    [16]
//   d_in[4] sqrt_alpha_ab f32    [16]
//   d_in[5] k_rep_ab      f32    [16]
// Output: energies f32 [M]

#define AB_D 1.8897261258369282

// ---------------- kernel 1: pack species to 2 bits/atom + zero output -------
__global__ __launch_bounds__(256) void pack_zero_kernel(
    const int* __restrict__ elem, int natoms, int nwords,
    unsigned* __restrict__ packed, float* __restrict__ out, int M)
{
    int g = blockIdx.x * blockDim.x + threadIdx.x;
    if (g < M) out[g] = 0.0f;
    if (packed != nullptr && g < nwords) {
        int base = g * 16;
        unsigned w = 0u;
        #pragma unroll
        for (int j = 0; j < 16; ++j) {
            int a = base + j;
            unsigned s = (a < natoms) ? ((unsigned)elem[a] & 3u) : 0u;
            w |= s << (2 * j);
        }
        packed[g] = w;
    }
}

// ---------------- kernel 2: main pair loop ----------------------------------
// LDS: [acc: M f32][tbl: 16 float4][packed: nwords u32 (optional)]
__global__ __launch_bounds__(512, 2) void rep_main_kernel(
    const int* __restrict__ nbr, const float* __restrict__ dist,
    const int* __restrict__ elem, const unsigned* __restrict__ packed_g,
    const float* __restrict__ y_ab, const float* __restrict__ sa_ab,
    const float* __restrict__ kr_ab,
    long long P, int M, int nwords, int ashift, int A,
    float* __restrict__ partials, float* __restrict__ out,
    int mode /*0 = write partial row, 1 = global atomics*/,
    int use_packed)
{
    extern __shared__ char smem[];
    float* acc = (float*)smem;
    size_t acc_bytes = ((size_t)M * 4 + 255) & ~(size_t)255;
    float4* tbl = (float4*)(smem + acc_bytes);
    unsigned* pk = (unsigned*)(smem + acc_bytes + 256);

    const int tid = threadIdx.x;
    const int nthr = blockDim.x;

    for (int m = tid; m < M; m += nthr) acc[m] = 0.0f;
    if (tid < 16) tbl[tid] = make_float4(y_ab[tid], sa_ab[tid], kr_ab[tid], 0.0f);
    if (use_packed) {
        for (int w = tid; w < nwords; w += nthr) pk[w] = packed_g[w];
    }
    __syncthreads();

    const float ABf   = (float)AB_D;
    const float RC    = (float)(5.2 * AB_D);
    const float RCINV = (float)(1.0 / (5.2 * AB_D));
    const int* nb0 = nbr;
    const int* nb1 = nbr + P;

    auto process = [&](int a0, int a1, float draw) {
        float d = fmaxf(draw, 1e-7f) * ABf;
        if (d < RC) {
            unsigned ua0 = (unsigned)a0, ua1 = (unsigned)a1;
            unsigned s0, s1;
            if (use_packed) {
                unsigned w0 = pk[ua0 >> 4];
                unsigned w1 = pk[ua1 >> 4];
                s0 = (w0 >> ((ua0 & 15u) * 2u)) & 3u;
                s1 = (w1 >> ((ua1 & 15u) * 2u)) & 3u;
            } else {
                s0 = (unsigned)elem[a0] & 3u;
                s1 = (unsigned)elem[a1] & 3u;
            }
            float4 t = tbl[s0 * 4u + s1];           // x=y, y=sqrt_alpha, z=k_rep
            float kr = t.z;
            float drep;
            if (kr == 1.5f)      drep = d * sqrtf(d);
            else if (kr == 1.0f) drep = d;
            else                 drep = __powf(d, kr);
            float x  = d * RCINV;
            float om = 1.0f - x * x;
            float e  = 1.0f - 1.0f / fmaxf(om, 1e-10f);
            // exp(-sa*drep) * exp(e) fused into one expf
            float rep = (t.x / d) * expf(e - t.y * drep);
            unsigned mol = (ashift >= 0) ? (ua0 >> ashift) : (ua0 / (unsigned)A);
            atomicAdd(&acc[mol], rep);
        }
    };

    long long P4 = P >> 2;
    long long gstride = (long long)gridDim.x * nthr;
    for (long long q = (long long)blockIdx.x * nthr + tid; q < P4; q += gstride) {
        int4   i0 = ((const int4*)nb0)[q];
        int4   i1 = ((const int4*)nb1)[q];
        float4 dv = ((const float4*)dist)[q];
        process(i0.x, i1.x, dv.x);
        process(i0.y, i1.y, dv.y);
        process(i0.z, i1.z, dv.z);
        process(i0.w, i1.w, dv.w);
    }
    // tail (P not divisible by 4) — handled by block 0
    long long tail0 = P4 << 2;
    if (blockIdx.x == 0) {
        for (long long p = tail0 + tid; p < P; p += nthr)
            process(nb0[p], nb1[p], dist[p]);
    }
    __syncthreads();

    if (mode == 0) {
        float* row = partials + (size_t)blockIdx.x * (size_t)M;
        for (int m = tid; m < M; m += nthr) row[m] = acc[m];
    } else {
        for (int m = tid; m < M; m += nthr) {
            float v = acc[m];
            if (v != 0.0f) atomicAdd(&out[m], v);
        }
    }
}

// ---------------- kernel 3: column-sum the partial rows ---------------------
__global__ __launch_bounds__(256) void reduce_kernel(
    const float* __restrict__ partials, float* __restrict__ out,
    int M, int nblk, int rows_per)
{
    int m = blockIdx.x * blockDim.x + threadIdx.x;
    if (m >= M) return;
    int r0 = blockIdx.y * rows_per;
    int r1 = r0 + rows_per;
    if (r1 > nblk) r1 = nblk;
    if (r0 >= r1) return;
    float s0 = 0.f, s1 = 0.f, s2 = 0.f, s3 = 0.f;
    int r = r0;
    for (; r + 3 < r1; r += 4) {
        s0 += partials[(size_t)(r + 0) * M + m];
        s1 += partials[(size_t)(r + 1) * M + m];
        s2 += partials[(size_t)(r + 2) * M + m];
        s3 += partials[(size_t)(r + 3) * M + m];
    }
    for (; r < r1; ++r) s0 += partials[(size_t)r * M + m];
    atomicAdd(&out[m], (s0 + s1) + (s2 + s3));
}

extern "C" void kernel_launch(void* const* d_in, const int* in_sizes, int n_in,
                              void* d_out, int out_size, void* d_ws, size_t ws_size,
                              hipStream_t stream)
{
    const int*   elem  = (const int*)d_in[0];
    const int*   nbr   = (const int*)d_in[1];
    const float* dist  = (const float*)d_in[2];
    const float* y_ab  = (const float*)d_in[3];
    const float* sa_ab = (const float*)d_in[4];
    const float* kr_ab = (const float*)d_in[5];
    float* out = (float*)d_out;

    const int natoms = in_sizes[0];
    const long long P = (long long)in_sizes[2];
    const int M = out_size;
    const int A = natoms / M;
    int ashift = -1;
    if (A > 0 && (A & (A - 1)) == 0) {
        int s = 0;
        while ((1 << s) < A) ++s;
        ashift = s;
    }
    const int nwords = (natoms + 15) / 16;

    // workspace layout: [packed: nwords u32 (256B aligned)][partials: nblk*M f32]
    size_t packed_bytes = ((size_t)nwords * 4 + 255) & ~(size_t)255;
    int use_packed = (ws_size >= packed_bytes) ? 1 : 0;
    unsigned* packed = use_packed ? (unsigned*)d_ws : nullptr;

    const int BLOCK = 512;
    int nblk = 512;
    float* partials = nullptr;
    int mode = 1; // global-atomic fallback
    if (use_packed) {
        size_t avail = ws_size - packed_bytes;
        size_t rowb = (size_t)M * 4;
        long long maxrows = (long long)(avail / rowb);
        if (maxrows >= 64) {
            nblk = (int)(maxrows < 512 ? maxrows : 512);
            partials = (float*)((char*)d_ws + packed_bytes);
            mode = 0;
        }
    }

    // kernel 1: pack + zero out
    {
        int total = (nwords > M) ? nwords : M;
        int g = (total + 255) / 256;
        hipLaunchKernelGGL(pack_zero_kernel, dim3(g), dim3(256), 0, stream,
                           elem, natoms, nwords, packed, out, M);
    }

    // kernel 2: main
    {
        size_t acc_bytes = ((size_t)M * 4 + 255) & ~(size_t)255;
        size_t smem = acc_bytes + 256 + (use_packed ? (size_t)nwords * 4 : 0);
        hipLaunchKernelGGL(rep_main_kernel, dim3(nblk), dim3(BLOCK), smem, stream,
                           nbr, dist, elem, packed, y_ab, sa_ab, kr_ab,
                           P, M, nwords, ashift, A, partials, out, mode, use_packed);
    }

    // kernel 3: reduce partial rows
    if (mode == 0) {
        const int SPLIT = 32;
        int rows_per = (nblk + SPLIT - 1) / SPLIT;
        dim3 grid((M + 255) / 256, SPLIT);
        hipLaunchKernelGGL(reduce_kernel, grid, dim3(256), 0, stream,
                           partials, out, M, nblk, rows_per);
    }
}